// Round 2
// baseline (643.127 us; speedup 1.0000x reference)
//
#include <hip/hip_runtime.h>

#define D_MODEL 2048
#define D_LATENT 512
#define NUM_HEADS 16
#define D_HEAD 128
#define BATCH 4
#define SEQ 2048
#define MTOK (BATCH*SEQ)   // 8192 tokens

typedef __bf16 bf16_t;
typedef __bf16 bf16x4 __attribute__((ext_vector_type(4)));
typedef __bf16 bf16x8 __attribute__((ext_vector_type(8)));
typedef float  f32x4  __attribute__((ext_vector_type(4)));

// async global->LDS, 16B per lane; LDS dst = wave-uniform base + lane*16 (m97 contract)
__device__ __forceinline__ void load_lds16(const bf16_t* g, bf16_t* l) {
  __builtin_amdgcn_global_load_lds(
      (const __attribute__((address_space(1))) void*)g,
      (__attribute__((address_space(3))) void*)l,
      16, 0, 0);
}

// ---------------- fp32 -> bf16 elementwise convert ----------------
__global__ void convert_f32_bf16_kernel(const float* __restrict__ src,
                                        bf16_t* __restrict__ dst, int n4) {
  int i = blockIdx.x * 256 + threadIdx.x;
  if (i >= n4) return;
  float4 v = *(const float4*)&src[(size_t)i * 4];
  bf16x4 o = { (bf16_t)v.x, (bf16_t)v.y, (bf16_t)v.z, (bf16_t)v.w };
  *(bf16x4*)&dst[(size_t)i * 4] = o;
}

// ------- weight transpose + convert: src f32 [R][C] -> dst bf16 [C][R] -------
__global__ void transpose_w_kernel(const float* __restrict__ src, bf16_t* __restrict__ dst,
                                   int R, int C) {
  __shared__ __align__(16) bf16_t tile[64][66];
  int rt = blockIdx.y * 64, ct = blockIdx.x * 64;
  int lc = threadIdx.x & 63, lr = threadIdx.x >> 6;
  for (int i = 0; i < 64; i += 4)
    tile[lr + i][lc] = (bf16_t)src[(size_t)(rt + lr + i) * C + ct + lc];
  __syncthreads();
  for (int i = 0; i < 64; i += 4)
    dst[(size_t)(ct + lr + i) * R + rt + lc] = tile[lc][lr + i];
}

// ------- V transpose: values bf16 [B*S][H*128] -> vt bf16 [B*H][128][S] -------
__global__ void transpose_v_kernel(const bf16_t* __restrict__ v, bf16_t* __restrict__ vt) {
  __shared__ __align__(16) bf16_t tile[64][66];
  int bh = blockIdx.z; int b = bh >> 4, h = bh & 15;
  int st = blockIdx.x * 64, dt = blockIdx.y * 64;
  int lc = threadIdx.x & 63, lr = threadIdx.x >> 6;
  const bf16_t* src = v + (size_t)b * SEQ * D_MODEL + h * D_HEAD;
  for (int i = 0; i < 64; i += 4)
    tile[lr + i][lc] = src[(size_t)(st + lr + i) * D_MODEL + dt + lc];
  __syncthreads();
  bf16_t* dst = vt + (size_t)bh * D_HEAD * SEQ;
  for (int i = 0; i < 64; i += 4)
    dst[(size_t)(dt + lr + i) * SEQ + st + lc] = tile[lc][lr + i];
}

// ---------------- GEMM (128^2, m97 structure) — kept for N=512 (down-proj) ----------------
template<typename OutT>
__global__ __launch_bounds__(256, 2) void gemm_bt_kernel(
    const bf16_t* __restrict__ A, const bf16_t* __restrict__ Wt,
    const float* __restrict__ bias, OutT* __restrict__ C,
    int M, int N, int K, float premul)
{
  __shared__ __align__(16) bf16_t As[128 * 32];
  __shared__ __align__(16) bf16_t Bs[128 * 32];
  int tid = threadIdx.x;
  int lane = tid & 63, wave = tid >> 6;
  int wr = (wave >> 1) * 64, wc = (wave & 1) * 64;
  size_t row0 = (size_t)blockIdx.x * 128, col0 = (size_t)blockIdx.y * 128;
  int lr = lane & 15, quad = lane >> 4, rq = quad * 4;

  f32x4 acc[4][4] = {};

  int srow = wave * 32 + (lane >> 2);
  int scol = ((lane & 3) ^ ((lane >> 3) & 3)) * 8;
  const bf16_t* Ag = A  + (row0 + srow) * K + scol;
  const bf16_t* Bg = Wt + (col0 + srow) * K + scol;
  bf16_t* Asw = As + wave * 1024;
  bf16_t* Bsw = Bs + wave * 1024;

  int rchunk = (quad ^ ((lr >> 1) & 3)) * 8;

  for (int k0 = 0; k0 < K; k0 += 32) {
    __syncthreads();
    load_lds16(Ag,          Asw);
    load_lds16(Ag + 16 * K, Asw + 512);
    load_lds16(Bg,          Bsw);
    load_lds16(Bg + 16 * K, Bsw + 512);
    Ag += 32; Bg += 32;
    __syncthreads();   // vmcnt(0) drained here -> LDS populated

    bf16x8 af[4], bfr[4];
    #pragma unroll
    for (int mi = 0; mi < 4; ++mi)
      af[mi] = *(const bf16x8*)&As[(wr + mi * 16 + lr) * 32 + rchunk];
    #pragma unroll
    for (int ni = 0; ni < 4; ++ni)
      bfr[ni] = *(const bf16x8*)&Bs[(wc + ni * 16 + lr) * 32 + rchunk];
    #pragma unroll
    for (int mi = 0; mi < 4; ++mi)
      #pragma unroll
      for (int ni = 0; ni < 4; ++ni)
        acc[mi][ni] = __builtin_amdgcn_mfma_f32_16x16x32_bf16(af[mi], bfr[ni], acc[mi][ni], 0, 0, 0);
  }

  #pragma unroll
  for (int ni = 0; ni < 4; ++ni) {
    int col = (int)col0 + wc + ni * 16 + lr;
    float bv = bias[col];
    #pragma unroll
    for (int mi = 0; mi < 4; ++mi) {
      #pragma unroll
      for (int r = 0; r < 4; ++r) {
        size_t row = row0 + wr + mi * 16 + rq + r;
        C[row * N + col] = (OutT)((acc[mi][ni][r] + bv) * premul);
      }
    }
  }
}

// ---------------- GEMM 256^2 8-phase (T2+T3+T4+T5), K compile-time ----------------
// 8 waves (2M x 4N), BK=64, LDS = 4 half-slots x 16KB per matrix = 128KB.
// Half-tile ring: A-half a_j (tile j>>1, M-half j&1) in slot j&3; same for B.
// Step s (4 phases, quadrants (M0,N0)(M0,N1)(M1,N0)(M1,N1)) reads a_{2s+wm}, b_{2s+(wn>>1)};
// stages p0:a_{2s+3} p1:b_{2s+3} p2:b_{2s+4} p3:a_{2s+4} — each issue is after the
// barrier closing the last reads of the slot it overwrites (A-half last read p2,
// B-half last read p1; tile s-1 halves done at step s-1's final barrier).
// One counted s_waitcnt vmcnt(4) per step (vmcnt(0) only at s==NT-2), before the
// step-boundary barrier -> next tile landed across all waves. Raw s_barrier (no
// vmcnt drain). LDS swizzle: 16B chunk c of row r holds global chunk c^(r&7);
// staged via pre-swizzled per-lane global source (linear LDS dest, m173 pattern).
template<typename OutT, int K>
__global__ __launch_bounds__(512, 2) void gemm8_kernel(
    const bf16_t* __restrict__ A, const bf16_t* __restrict__ Wt,
    const float* __restrict__ bias, OutT* __restrict__ C,
    int M, int N, float premul)
{
  constexpr int NT = K / 64;
  __shared__ __align__(16) bf16_t AS[4 * 8192];
  __shared__ __align__(16) bf16_t BS[4 * 8192];
  int tid = threadIdx.x, lane = tid & 63, wave = tid >> 6;
  int wm = wave >> 2, wn = wave & 3;
  int lr = lane & 15, quad = lane >> 4, rq = quad * 4;
  int rsw = lr & 7;

  int mtiles = M >> 8;
  int nwg = gridDim.x;
  int wg = blockIdx.x;
  int swz = (wg & 7) * (nwg >> 3) + (wg >> 3);   // nwg % 8 == 0 for all our shapes
  size_t row0 = (size_t)(swz % mtiles) * 256;
  size_t col0 = (size_t)(swz / mtiles) * 256;

  // staging source: per-thread row within a 64-row q-block + pre-swizzled chunk
  int srow = (wave << 3) + (lane >> 3);           // 0..63 ; (srow & 7) == lane>>3
  int scol = ((lane & 7) ^ (lane >> 3)) * 8;      // source chunk = dest ^ (row&7)
  const bf16_t* Abase = A  + (row0 + srow) * K + scol;
  const bf16_t* Bbase = Wt + (col0 + srow) * K + scol;

  auto stageA = [&](int j) {
    int kt = j >> 1, half = j & 1, slot = j & 3;
    const bf16_t* g = Abase + (size_t)(half * 128) * K + kt * 64;
    bf16_t* l = AS + slot * 8192 + wave * 512;
    load_lds16(g,                l);
    load_lds16(g + (size_t)64 * K, l + 4096);
  };
  auto stageB = [&](int j) {
    int kt = j >> 1, half = j & 1, slot = j & 3;
    const bf16_t* g = Bbase + (size_t)(half * 128) * K + kt * 64;
    bf16_t* l = BS + slot * 8192 + wave * 512;
    load_lds16(g,                l);
    load_lds16(g + (size_t)64 * K, l + 4096);
  };

  f32x4 acc[8][4] = {};
  bf16x8 aF[4][2], bF[2][2][2];   // bF[Nh][n][kh]

  // prologue: units a0,b0,a1,b1 (tile 0) + a2,b2 (tile 1 half 0)
  stageA(0); stageB(0); stageA(1); stageB(1); stageA(2); stageB(2);
  asm volatile("s_waitcnt vmcnt(4)" ::: "memory");   // tile 0 landed; a2,b2 in flight
  __builtin_amdgcn_s_barrier();

  for (int s = 0; s < NT; ++s) {
    const bf16_t* Asl = AS + ((2 * s + wm) & 3) * 8192;
    const bf16_t* Bsl = BS + ((2 * s + (wn >> 1)) & 3) * 8192;

    // ---- phase 0: quadrant (M0,N0); load A-M0 (8) + B-N0 (4); stage a_{2s+3}
    #pragma unroll
    for (int m = 0; m < 4; ++m)
      #pragma unroll
      for (int kh = 0; kh < 2; ++kh)
        aF[m][kh] = *(const bf16x8*)&Asl[(m * 16 + lr) * 64 + (((kh * 4 + quad) ^ rsw) * 8)];
    #pragma unroll
    for (int n = 0; n < 2; ++n)
      #pragma unroll
      for (int kh = 0; kh < 2; ++kh)
        bF[0][n][kh] = *(const bf16x8*)&Bsl[((wn & 1) * 64 + n * 16 + lr) * 64 + (((kh * 4 + quad) ^ rsw) * 8)];
    if (2 * s + 3 < 2 * NT) stageA(2 * s + 3);
    __builtin_amdgcn_s_barrier();
    asm volatile("s_waitcnt lgkmcnt(0)" ::: "memory");
    __builtin_amdgcn_sched_barrier(0);
    __builtin_amdgcn_s_setprio(1);
    #pragma unroll
    for (int m = 0; m < 4; ++m)
      #pragma unroll
      for (int n = 0; n < 2; ++n)
        #pragma unroll
        for (int kh = 0; kh < 2; ++kh)
          acc[m][n] = __builtin_amdgcn_mfma_f32_16x16x32_bf16(aF[m][kh], bF[0][n][kh], acc[m][n], 0, 0, 0);
    __builtin_amdgcn_s_setprio(0);
    __builtin_amdgcn_s_barrier();

    // ---- phase 1: quadrant (M0,N1); load B-N1 (4); stage b_{2s+3}
    #pragma unroll
    for (int n = 0; n < 2; ++n)
      #pragma unroll
      for (int kh = 0; kh < 2; ++kh)
        bF[1][n][kh] = *(const bf16x8*)&Bsl[((wn & 1) * 64 + 32 + n * 16 + lr) * 64 + (((kh * 4 + quad) ^ rsw) * 8)];
    if (2 * s + 3 < 2 * NT) stageB(2 * s + 3);
    __builtin_amdgcn_s_barrier();
    asm volatile("s_waitcnt lgkmcnt(0)" ::: "memory");
    __builtin_amdgcn_sched_barrier(0);
    __builtin_amdgcn_s_setprio(1);
    #pragma unroll
    for (int m = 0; m < 4; ++m)
      #pragma unroll
      for (int n = 0; n < 2; ++n)
        #pragma unroll
        for (int kh = 0; kh < 2; ++kh)
          acc[m][2 + n] = __builtin_amdgcn_mfma_f32_16x16x32_bf16(aF[m][kh], bF[1][n][kh], acc[m][2 + n], 0, 0, 0);
    __builtin_amdgcn_s_setprio(0);
    __builtin_amdgcn_s_barrier();

    // ---- phase 2: quadrant (M1,N0); load A-M1 (8); stage b_{2s+4}
    #pragma unroll
    for (int m = 0; m < 4; ++m)
      #pragma unroll
      for (int kh = 0; kh < 2; ++kh)
        aF[m][kh] = *(const bf16x8*)&Asl[(64 + m * 16 + lr) * 64 + (((kh * 4 + quad) ^ rsw) * 8)];
    if (2 * s + 4 < 2 * NT) stageB(2 * s + 4);
    __builtin_amdgcn_s_barrier();
    asm volatile("s_waitcnt lgkmcnt(0)" ::: "memory");
    __builtin_amdgcn_sched_barrier(0);
    __builtin_amdgcn_s_setprio(1);
    #pragma unroll
    for (int m = 0; m < 4; ++m)
      #pragma unroll
      for (int n = 0; n < 2; ++n)
        #pragma unroll
        for (int kh = 0; kh < 2; ++kh)
          acc[4 + m][n] = __builtin_amdgcn_mfma_f32_16x16x32_bf16(aF[m][kh], bF[0][n][kh], acc[4 + m][n], 0, 0, 0);
    __builtin_amdgcn_s_setprio(0);
    __builtin_amdgcn_s_barrier();

    // ---- phase 3: quadrant (M1,N1); no loads; stage a_{2s+4}
    if (2 * s + 4 < 2 * NT) stageA(2 * s + 4);
    __builtin_amdgcn_s_barrier();
    __builtin_amdgcn_s_setprio(1);
    #pragma unroll
    for (int m = 0; m < 4; ++m)
      #pragma unroll
      for (int n = 0; n < 2; ++n)
        #pragma unroll
        for (int kh = 0; kh < 2; ++kh)
          acc[4 + m][2 + n] = __builtin_amdgcn_mfma_f32_16x16x32_bf16(aF[m][kh], bF[1][n][kh], acc[4 + m][2 + n], 0, 0, 0);
    __builtin_amdgcn_s_setprio(0);
    // step-boundary wait: tile s+1 (units <= 2s+3) landed; 2 newest units may fly
    if (s < NT - 2)       asm volatile("s_waitcnt vmcnt(4)" ::: "memory");
    else if (s == NT - 2) asm volatile("s_waitcnt vmcnt(0)" ::: "memory");
    __builtin_amdgcn_s_barrier();
  }

  // epilogue: row = row0 + wm*128 + Mh*64 + m*16 + rq + r ; col = col0 + wn*64 + Nh*32 + n*16 + lr
  #pragma unroll
  for (int mh = 0; mh < 2; ++mh)
    #pragma unroll
    for (int nh = 0; nh < 2; ++nh)
      #pragma unroll
      for (int n = 0; n < 2; ++n) {
        int col = (int)col0 + wn * 64 + nh * 32 + n * 16 + lr;
        float bv = bias[col];
        #pragma unroll
        for (int m = 0; m < 4; ++m)
          #pragma unroll
          for (int r = 0; r < 4; ++r) {
            size_t row = row0 + wm * 128 + mh * 64 + m * 16 + rq + r;
            C[row * N + col] = (OutT)((acc[mh * 4 + m][nh * 2 + n][r] + bv) * premul);
          }
      }
}

// ---------------- flash attention (unchanged from R1-best) ----------------
__global__ __launch_bounds__(256, 2) void attention_kernel(
    const bf16_t* __restrict__ q, const bf16_t* __restrict__ keys,
    const bf16_t* __restrict__ vt, bf16_t* __restrict__ ctx)
{
  __shared__ __align__(16) bf16_t KP[128 * 72];  // union: Ks[64][136] / Ps[128][72]
  __shared__ __align__(16) bf16_t Vs[128][72];   // [d][key]
  bf16_t (*Ks)[136] = (bf16_t (*)[136])KP;
  bf16_t (*Ps)[72]  = (bf16_t (*)[72])KP;
  int bh = blockIdx.y; int b = bh >> 4, h = bh & 15;
  int qt = blockIdx.x;
  int tid = threadIdx.x, lane = tid & 63, wave = tid >> 6;
  int lr = lane & 15, quad = lane >> 4, kq = quad * 8, rq = quad * 4;

  const bf16_t* qg = q    + (size_t)(b * SEQ + qt * 128) * D_MODEL + h * D_HEAD;
  const bf16_t* kg = keys + (size_t)b * SEQ * D_MODEL + h * D_HEAD;
  const bf16_t* vg = vt   + (size_t)bh * D_HEAD * SEQ;

  bf16x8 qf[2][4];
  #pragma unroll
  for (int mi = 0; mi < 2; ++mi)
    #pragma unroll
    for (int ks = 0; ks < 4; ++ks)
      qf[mi][ks] = *(const bf16x8*)&qg[(size_t)(wave*32 + mi*16 + lr) * D_MODEL + ks*32 + kq];

  bf16x8 kreg[4], vreg[4];
  const bf16_t* kp4[4];
  const bf16_t* vp4[4];
  bf16_t* kd4[4];
  bf16_t* vd4[4];
  #pragma unroll
  for (int i = 0; i < 4; ++i) {
    int c = tid + i * 256;
    int r = c >> 4, kc = (c & 15) * 8;
    kp4[i] = kg + (size_t)r * D_MODEL + kc;
    kd4[i] = &Ks[r][kc];
    int d = c >> 3, vc = (c & 7) * 8;
    vp4[i] = vg + (size_t)d * SEQ + vc;
    vd4[i] = &Vs[d][vc];
  }
  #pragma unroll
  for (int i = 0; i < 4; ++i) {
    kreg[i] = *(const bf16x8*)kp4[i];
    vreg[i] = *(const bf16x8*)vp4[i];
  }

  f32x4 accO[2][8] = {};
  float m2[2]   = {-1e30f, -1e30f};
  float lsum[2] = {0.f, 0.f};

  for (int kt = 0; kt < SEQ/64; ++kt) {
    __syncthreads();
    #pragma unroll
    for (int i = 0; i < 4; ++i) {
      *(bf16x8*)kd4[i] = kreg[i];
      *(bf16x8*)vd4[i] = vreg[i];
    }
    __syncthreads();

    f32x4 sc[2][4] = {};
    #pragma unroll
    for (int ks = 0; ks < 4; ++ks) {
      bf16x8 kf[4];
      #pragma unroll
      for (int ni = 0; ni < 4; ++ni) kf[ni] = *(const bf16x8*)&Ks[ni*16 + lr][ks*32 + kq];
      __builtin_amdgcn_s_setprio(1);
      #pragma unroll
      for (int mi = 0; mi < 2; ++mi)
        #pragma unroll
        for (int ni = 0; ni < 4; ++ni)
          sc[mi][ni] = __builtin_amdgcn_mfma_f32_16x16x32_bf16(kf[ni], qf[mi][ks], sc[mi][ni], 0, 0, 0);
      __builtin_amdgcn_s_setprio(0);
    }

    __syncthreads();

    if (kt + 1 < SEQ/64) {
      #pragma unroll
      for (int i = 0; i < 4; ++i) {
        kp4[i] += 64 * D_MODEL;
        vp4[i] += 64;
        kreg[i] = *(const bf16x8*)kp4[i];
        vreg[i] = *(const bf16x8*)vp4[i];
      }
    }

    #pragma unroll
    for (int mi = 0; mi < 2; ++mi) {
      float rm = sc[mi][0][0];
      #pragma unroll
      for (int ni = 0; ni < 4; ++ni)
        #pragma unroll
        for (int r = 0; r < 4; ++r) rm = fmaxf(rm, sc[mi][ni][r]);
      rm = fmaxf(rm, __shfl_xor(rm, 16, 64));
      rm = fmaxf(rm, __shfl_xor(rm, 32, 64));

      if (!__all(rm - m2[mi] <= 8.0f)) {
        float mnew  = fmaxf(m2[mi], rm);
        float alpha = exp2f(m2[mi] - mnew);
        m2[mi] = mnew;
        lsum[mi] *= alpha;
        float ar[4];
        #pragma unroll
        for (int r = 0; r < 4; ++r) ar[r] = __shfl(alpha, rq + r, 16);
        #pragma unroll
        for (int nd = 0; nd < 8; ++nd)
          #pragma unroll
          for (int r = 0; r < 4; ++r) accO[mi][nd][r] *= ar[r];
      }

      float rs = 0.f;
      int prow = wave*32 + mi*16 + lr;
      #pragma unroll
      for (int ni = 0; ni < 4; ++ni) {
        float p0 = exp2f(sc[mi][ni][0] - m2[mi]);
        float p1 = exp2f(sc[mi][ni][1] - m2[mi]);
        float p2 = exp2f(sc[mi][ni][2] - m2[mi]);
        float p3 = exp2f(sc[mi][ni][3] - m2[mi]);
        rs += (p0 + p1) + (p2 + p3);
        bf16x4 pk = { (bf16_t)p0, (bf16_t)p1, (bf16_t)p2, (bf16_t)p3 };
        *(bf16x4*)&Ps[prow][ni*16 + rq] = pk;
      }
      rs += __shfl_xor(rs, 16, 64);
      rs += __shfl_xor(rs, 32, 64);
      lsum[mi] += rs;
    }

    #pragma unroll
    for (int ks2 = 0; ks2 < 2; ++ks2) {
      bf16x8 pf[2], vf[8];
      #pragma unroll
      for (int mi = 0; mi < 2; ++mi)
        pf[mi] = *(const bf16x8*)&Ps[wave*32 + mi*16 + lr][ks2*32 + kq];
      #pragma unroll
      for (int nd = 0; nd < 8; ++nd)
        vf[nd] = *(const bf16x8*)&Vs[nd*16 + lr][ks2*32 + kq];
      __builtin_amdgcn_s_setprio(1);
      #pragma unroll
      for (int mi = 0; mi < 2; ++mi)
        #pragma unroll
        for (int nd = 0; nd < 8; ++nd)
          accO[mi][nd] = __builtin_amdgcn_mfma_f32_16x16x32_bf16(pf[mi], vf[nd], accO[mi][nd], 0, 0, 0);
      __builtin_amdgcn_s_setprio(0);
    }
  }

  bf16_t* og = ctx + (size_t)(b * SEQ + qt * 128) * D_MODEL + h * D_HEAD;
  #pragma unroll
  for (int mi = 0; mi < 2; ++mi) {
    float inv[4];
    #pragma unroll
    for (int r = 0; r < 4; ++r) inv[r] = 1.0f / __shfl(lsum[mi], rq + r, 16);
    #pragma unroll
    for (int r = 0; r < 4; ++r) {
      int row = wave*32 + mi*16 + rq + r;
      #pragma unroll
      for (int nd = 0; nd < 8; ++nd)
        og[(size_t)row * D_MODEL + nd*16 + lr] = (bf16_t)(accO[mi][nd][r] * inv[r]);
    }
  }
}

extern "C" void kernel_launch(void* const* d_in, const int* in_sizes, int n_in,
                              void* d_out, int out_size, void* d_ws, size_t ws_size,
                              hipStream_t stream) {
  const float* x      = (const float*)d_in[0];
  const float* W_down = (const float*)d_in[1];
  const float* b_down = (const float*)d_in[2];
  const float* W_uk   = (const float*)d_in[3];
  const float* b_uk   = (const float*)d_in[4];
  const float* W_uv   = (const float*)d_in[5];
  const float* b_uv   = (const float*)d_in[6];
  const float* W_q    = (const float*)d_in[7];
  const float* b_q    = (const float*)d_in[8];
  const float* W_o    = (const float*)d_in[9];
  const float* b_o    = (const float*)d_in[10];
  float* out = (float*)d_out;

  char* ws = (char*)d_ws;
  bf16_t* xb      = (bf16_t*)ws;  ws += (size_t)MTOK*D_MODEL*2;
  bf16_t* Wt_down = (bf16_t*)ws;  ws += (size_t)D_LATENT*D_MODEL*2;
  bf16_t* Wt_uk   = (bf16_t*)ws;  ws += (size_t)D_MODEL*D_LATENT*2;
  bf16_t* Wt_uv   = (bf16_t*)ws;  ws += (size_t)D_MODEL*D_LATENT*2;
  bf16_t* Wt_q    = (bf16_t*)ws;  ws += (size_t)D_MODEL*D_MODEL*2;
  bf16_t* Wt_o    = (bf16_t*)ws;  ws += (size_t)D_MODEL*D_MODEL*2;
  bf16_t* lat     = (bf16_t*)ws;  ws += (size_t)MTOK*D_LATENT*2;
  bf16_t* keys    = (bf16_t*)ws;  ws += (size_t)MTOK*D_MODEL*2;
  bf16_t* vals    = (bf16_t*)ws;  ws += (size_t)MTOK*D_MODEL*2;
  bf16_t* qm      = (bf16_t*)ws;  ws += (size_t)MTOK*D_MODEL*2;
  bf16_t* vtm     = (bf16_t*)ws;  ws += (size_t)MTOK*D_MODEL*2;
  bf16_t* ctx     = vals;  // vals dead after transpose_v

  const float cs = 0.0883883476483184f * 1.44269504089f;  // 1/sqrt(128) * log2(e)

  convert_f32_bf16_kernel<<<(MTOK*D_MODEL/4 + 255)/256, 256, 0, stream>>>(x, xb, MTOK*D_MODEL/4);

  transpose_w_kernel<<<dim3(D_LATENT/64, D_MODEL/64), 256, 0, stream>>>(W_down, Wt_down, D_MODEL, D_LATENT);
  transpose_w_kernel<<<dim3(D_MODEL/64, D_LATENT/64), 256, 0, stream>>>(W_uk,   Wt_uk,   D_LATENT, D_MODEL);
  transpose_w_kernel<<<dim3(D_MODEL/64, D_LATENT/64), 256, 0, stream>>>(W_uv,   Wt_uv,   D_LATENT, D_MODEL);
  transpose_w_kernel<<<dim3(D_MODEL/64, D_MODEL/64),  256, 0, stream>>>(W_q,    Wt_q,    D_MODEL,  D_MODEL);
  transpose_w_kernel<<<dim3(D_MODEL/64, D_MODEL/64),  256, 0, stream>>>(W_o,    Wt_o,    D_MODEL,  D_MODEL);

  // down-proj (N=512): 256^2 tiles would give only 64 wg -> keep 128^2 kernel
  gemm_bt_kernel<bf16_t><<<dim3(MTOK/128, D_LATENT/128), 256, 0, stream>>>(xb,  Wt_down, b_down, lat,  MTOK, D_LATENT, D_MODEL, 1.0f);

  // 256^2 8-phase for the four big GEMMs (grid = 32x8 = 256 wg = 1/CU)
  gemm8_kernel<bf16_t, 512><<<(MTOK/256)*(D_MODEL/256), 512, 0, stream>>>(lat, Wt_uk, b_uk, keys, MTOK, D_MODEL, 1.0f);
  gemm8_kernel<bf16_t, 512><<<(MTOK/256)*(D_MODEL/256), 512, 0, stream>>>(lat, Wt_uv, b_uv, vals, MTOK, D_MODEL, 1.0f);
  gemm8_kernel<bf16_t, 2048><<<(MTOK/256)*(D_MODEL/256), 512, 0, stream>>>(xb, Wt_q, b_q, qm, MTOK, D_MODEL, cs);

  transpose_v_kernel<<<dim3(SEQ/64, D_HEAD/64, BATCH*NUM_HEADS), 256, 0, stream>>>(vals, vtm);

  attention_kernel<<<dim3(SEQ/128, BATCH*NUM_HEADS), 256, 0, stream>>>(qm, keys, vtm, ctx);

  gemm8_kernel<float, 2048><<<(MTOK/256)*(D_MODEL/256), 512, 0, stream>>>(ctx, Wt_o, b_o, out, MTOK, D_MODEL, 1.0f);
}

// Round 3
// 614.150 us; speedup vs baseline: 1.0472x; 1.0472x over previous
//
#include <hip/hip_runtime.h>

#define D_MODEL 2048
#define D_LATENT 512
#define NUM_HEADS 16
#define D_HEAD 128
#define BATCH 4
#define SEQ 2048
#define MTOK (BATCH*SEQ)   // 8192 tokens

typedef __bf16 bf16_t;
typedef __bf16 bf16x4 __attribute__((ext_vector_type(4)));
typedef __bf16 bf16x8 __attribute__((ext_vector_type(8)));
typedef float  f32x4  __attribute__((ext_vector_type(4)));

// async global->LDS, 16B per lane; LDS dst = wave-uniform base + lane*16 (m97 contract)
__device__ __forceinline__ void load_lds16(const bf16_t* g, bf16_t* l) {
  __builtin_amdgcn_global_load_lds(
      (const __attribute__((address_space(1))) void*)g,
      (__attribute__((address_space(3))) void*)l,
      16, 0, 0);
}

// ---------------- fp32 -> bf16 elementwise convert ----------------
__global__ void convert_f32_bf16_kernel(const float* __restrict__ src,
                                        bf16_t* __restrict__ dst, int n4) {
  int i = blockIdx.x * 256 + threadIdx.x;
  if (i >= n4) return;
  float4 v = *(const float4*)&src[(size_t)i * 4];
  bf16x4 o = { (bf16_t)v.x, (bf16_t)v.y, (bf16_t)v.z, (bf16_t)v.w };
  *(bf16x4*)&dst[(size_t)i * 4] = o;
}

// ------- weight transpose + convert: src f32 [R][C] -> dst bf16 [C][R] -------
__global__ void transpose_w_kernel(const float* __restrict__ src, bf16_t* __restrict__ dst,
                                   int R, int C) {
  __shared__ __align__(16) bf16_t tile[64][66];
  int rt = blockIdx.y * 64, ct = blockIdx.x * 64;
  int lc = threadIdx.x & 63, lr = threadIdx.x >> 6;
  for (int i = 0; i < 64; i += 4)
    tile[lr + i][lc] = (bf16_t)src[(size_t)(rt + lr + i) * C + ct + lc];
  __syncthreads();
  for (int i = 0; i < 64; i += 4)
    dst[(size_t)(ct + lr + i) * R + rt + lc] = tile[lc][lr + i];
}

// ------- V transpose: values bf16 [B*S][H*128] -> vt bf16 [B*H][128][S] -------
__global__ void transpose_v_kernel(const bf16_t* __restrict__ v, bf16_t* __restrict__ vt) {
  __shared__ __align__(16) bf16_t tile[64][66];
  int bh = blockIdx.z; int b = bh >> 4, h = bh & 15;
  int st = blockIdx.x * 64, dt = blockIdx.y * 64;
  int lc = threadIdx.x & 63, lr = threadIdx.x >> 6;
  const bf16_t* src = v + (size_t)b * SEQ * D_MODEL + h * D_HEAD;
  for (int i = 0; i < 64; i += 4)
    tile[lr + i][lc] = src[(size_t)(st + lr + i) * D_MODEL + dt + lc];
  __syncthreads();
  bf16_t* dst = vt + (size_t)bh * D_HEAD * SEQ;
  for (int i = 0; i < 64; i += 4)
    dst[(size_t)(dt + lr + i) * SEQ + st + lc] = tile[lc][lr + i];
}

// ---------------- GEMM: C[M][N] = (A[M][K] @ Wt[N][K]^T + bias[N]) * premul ----------------
// 128x128 tile, 4 waves, BK=32, global_load_lds width-16 staging (m97 structure).
// R2's 256^2 8-phase port regressed (~650 TF vs this ~900) -> reverted; the 8-phase
// schedule needs the exact m201 interleave which a blind port does not reproduce.
template<typename OutT>
__global__ __launch_bounds__(256, 2) void gemm_bt_kernel(
    const bf16_t* __restrict__ A, const bf16_t* __restrict__ Wt,
    const float* __restrict__ bias, OutT* __restrict__ C,
    int M, int N, int K, float premul)
{
  __shared__ __align__(16) bf16_t As[128 * 32];
  __shared__ __align__(16) bf16_t Bs[128 * 32];
  int tid = threadIdx.x;
  int lane = tid & 63, wave = tid >> 6;
  int wr = (wave >> 1) * 64, wc = (wave & 1) * 64;
  size_t row0 = (size_t)blockIdx.x * 128, col0 = (size_t)blockIdx.y * 128;
  int lr = lane & 15, quad = lane >> 4, rq = quad * 4;

  f32x4 acc[4][4] = {};

  int srow = wave * 32 + (lane >> 2);
  int scol = ((lane & 3) ^ ((lane >> 3) & 3)) * 8;
  const bf16_t* Ag = A  + (row0 + srow) * K + scol;
  const bf16_t* Bg = Wt + (col0 + srow) * K + scol;
  bf16_t* Asw = As + wave * 1024;
  bf16_t* Bsw = Bs + wave * 1024;

  int rchunk = (quad ^ ((lr >> 1) & 3)) * 8;

  for (int k0 = 0; k0 < K; k0 += 32) {
    __syncthreads();
    load_lds16(Ag,          Asw);
    load_lds16(Ag + 16 * K, Asw + 512);
    load_lds16(Bg,          Bsw);
    load_lds16(Bg + 16 * K, Bsw + 512);
    Ag += 32; Bg += 32;
    __syncthreads();   // vmcnt(0) drained here -> LDS populated

    bf16x8 af[4], bfr[4];
    #pragma unroll
    for (int mi = 0; mi < 4; ++mi)
      af[mi] = *(const bf16x8*)&As[(wr + mi * 16 + lr) * 32 + rchunk];
    #pragma unroll
    for (int ni = 0; ni < 4; ++ni)
      bfr[ni] = *(const bf16x8*)&Bs[(wc + ni * 16 + lr) * 32 + rchunk];
    #pragma unroll
    for (int mi = 0; mi < 4; ++mi)
      #pragma unroll
      for (int ni = 0; ni < 4; ++ni)
        acc[mi][ni] = __builtin_amdgcn_mfma_f32_16x16x32_bf16(af[mi], bfr[ni], acc[mi][ni], 0, 0, 0);
  }

  // epilogue: C/D layout col=lane&15, row=quad*4+r  [m89-verified]
  #pragma unroll
  for (int ni = 0; ni < 4; ++ni) {
    int col = (int)col0 + wc + ni * 16 + lr;
    float bv = bias[col];
    #pragma unroll
    for (int mi = 0; mi < 4; ++mi) {
      #pragma unroll
      for (int r = 0; r < 4; ++r) {
        size_t row = row0 + wr + mi * 16 + rq + r;
        C[row * N + col] = (OutT)((acc[mi][ni][r] + bv) * premul);
      }
    }
  }
}

// ---------------- flash attention: one block per (b,h, 128 q rows) ----------------
// S^T orientation (q = lane&15); log2-domain softmax (Q pre-scaled in its GEMM).
// R3: T2 XOR-swizzle (m214 recipe: byte ^= ((row&7)<<4), pad-free tiles) on all
// LDS surfaces; Ks[64][128] / Ps[128][64] alias exactly (16KB); Vs[128][64] 16KB.
// LDS 36.9 -> 32KB (4 blocks/CU now LDS-feasible).
// Element mapping (both sides): chunk c (16B) of row r lives at c ^ (r&7)
// (low-3-bit XOR of the chunk index).  Verified write/read consistency:
//   K: write (r, c=tid&15) / read (row=ni*16+lr, c=ks*4+quad); row&7 == lr&7.
//   V: write (d, c=tid&7)  / read (d=nd*16+lr,  c=ks2*4+quad).
//   P: write b64 at key=ni*16+quad*4 -> chunk ni*2+(quad>>1), off (quad&1)*4;
//      read  (row, c=ks2*4+quad).
__global__ __launch_bounds__(256, 2) void attention_kernel(
    const bf16_t* __restrict__ q, const bf16_t* __restrict__ keys,
    const bf16_t* __restrict__ vt, bf16_t* __restrict__ ctx)
{
  __shared__ __align__(16) bf16_t KP[64 * 128];   // union: Ks[64][128] / Ps[128][64]
  __shared__ __align__(16) bf16_t VS[128 * 64];   // [d][key]
  int bh = blockIdx.y; int b = bh >> 4, h = bh & 15;
  int qt = blockIdx.x;
  int tid = threadIdx.x, lane = tid & 63, wave = tid >> 6;
  int lr = lane & 15, quad = lane >> 4, kq = quad * 8, rq = quad * 4;
  int l7 = lr & 7;

  const bf16_t* qg = q    + (size_t)(b * SEQ + qt * 128) * D_MODEL + h * D_HEAD;
  const bf16_t* kg = keys + (size_t)b * SEQ * D_MODEL + h * D_HEAD;
  const bf16_t* vg = vt   + (size_t)bh * D_HEAD * SEQ;

  // Q fragments (B operand; layout: n=lane&15, k=quad*8+j)
  bf16x8 qf[2][4];
  #pragma unroll
  for (int mi = 0; mi < 2; ++mi)
    #pragma unroll
    for (int ks = 0; ks < 4; ++ks)
      qf[mi][ks] = *(const bf16x8*)&qg[(size_t)(wave*32 + mi*16 + lr) * D_MODEL + ks*32 + kq];

  // staging coords + prefetch registers (T14); LDS dests pre-swizzled
  bf16x8 kreg[4], vreg[4];
  const bf16_t* kp4[4];
  const bf16_t* vp4[4];
  bf16_t* kd4[4];
  bf16_t* vd4[4];
  #pragma unroll
  for (int i = 0; i < 4; ++i) {
    int c = tid + i * 256;
    int r = c >> 4, kc = c & 15;                    // K: 64 rows x 16 chunks
    kp4[i] = kg + (size_t)r * D_MODEL + kc * 8;
    kd4[i] = &KP[r * 128 + ((kc ^ (r & 7)) * 8)];
    int d = c >> 3, vc = c & 7;                     // V: 128 rows x 8 chunks
    vp4[i] = vg + (size_t)d * SEQ + vc * 8;
    vd4[i] = &VS[d * 64 + ((vc ^ (d & 7)) * 8)];
  }
  #pragma unroll
  for (int i = 0; i < 4; ++i) {
    kreg[i] = *(const bf16x8*)kp4[i];
    vreg[i] = *(const bf16x8*)vp4[i];
  }

  f32x4 accO[2][8] = {};                  // O[q=base+rq+r][d=nd*16+lr]
  float m2[2]   = {-1e30f, -1e30f};       // running max (log2 domain), q = base+(lane&15)
  float lsum[2] = {0.f, 0.f};

  for (int kt = 0; kt < SEQ/64; ++kt) {
    __syncthreads();   // all waves done with prev tile's Ps/Vs reads; prefetch arrived
    #pragma unroll
    for (int i = 0; i < 4; ++i) {
      *(bf16x8*)kd4[i] = kreg[i];
      *(bf16x8*)vd4[i] = vreg[i];
    }
    __syncthreads();   // staging visible block-wide

    // S^T = K @ Q^T : sc[mi][ni][r] at key=ni*16+rq+r, q=wave*32+mi*16+lr
    f32x4 sc[2][4] = {};
    #pragma unroll
    for (int ks = 0; ks < 4; ++ks) {
      bf16x8 kf[4];
      #pragma unroll
      for (int ni = 0; ni < 4; ++ni)
        kf[ni] = *(const bf16x8*)&KP[(ni*16 + lr) * 128 + (((ks*4 + quad) ^ l7) * 8)];
      __builtin_amdgcn_s_setprio(1);
      #pragma unroll
      for (int mi = 0; mi < 2; ++mi)
        #pragma unroll
        for (int ni = 0; ni < 4; ++ni)
          sc[mi][ni] = __builtin_amdgcn_mfma_f32_16x16x32_bf16(kf[ni], qf[mi][ks], sc[mi][ni], 0, 0, 0);
      __builtin_amdgcn_s_setprio(0);
    }

    __syncthreads();   // all kf reads of Ks done before P overwrites it

    // T14: issue next tile's global loads now; they hide under softmax+PV
    if (kt + 1 < SEQ/64) {
      #pragma unroll
      for (int i = 0; i < 4; ++i) {
        kp4[i] += 64 * D_MODEL;
        vp4[i] += 64;
        kreg[i] = *(const bf16x8*)kp4[i];
        vreg[i] = *(const bf16x8*)vp4[i];
      }
    }

    // online softmax (log2 domain; scores already scaled by cs in the q-GEMM)
    #pragma unroll
    for (int mi = 0; mi < 2; ++mi) {
      float rm = sc[mi][0][0];
      #pragma unroll
      for (int ni = 0; ni < 4; ++ni)
        #pragma unroll
        for (int r = 0; r < 4; ++r) rm = fmaxf(rm, sc[mi][ni][r]);
      rm = fmaxf(rm, __shfl_xor(rm, 16, 64));
      rm = fmaxf(rm, __shfl_xor(rm, 32, 64));

      // T13 defer-max: skip rescale when the whole wave's rows grew < 2^8
      if (!__all(rm - m2[mi] <= 8.0f)) {
        float mnew  = fmaxf(m2[mi], rm);
        float alpha = exp2f(m2[mi] - mnew);
        m2[mi] = mnew;
        lsum[mi] *= alpha;
        float ar[4];
        #pragma unroll
        for (int r = 0; r < 4; ++r) ar[r] = __shfl(alpha, rq + r, 16);
        #pragma unroll
        for (int nd = 0; nd < 8; ++nd)
          #pragma unroll
          for (int r = 0; r < 4; ++r) accO[mi][nd][r] *= ar[r];
      }

      float rs = 0.f;
      int prow = wave*32 + mi*16 + lr;
      int pbase = prow * 64;
      int psw = prow & 7;
      #pragma unroll
      for (int ni = 0; ni < 4; ++ni) {
        float p0 = exp2f(sc[mi][ni][0] - m2[mi]);
        float p1 = exp2f(sc[mi][ni][1] - m2[mi]);
        float p2 = exp2f(sc[mi][ni][2] - m2[mi]);
        float p3 = exp2f(sc[mi][ni][3] - m2[mi]);
        rs += (p0 + p1) + (p2 + p3);
        bf16x4 pk = { (bf16_t)p0, (bf16_t)p1, (bf16_t)p2, (bf16_t)p3 };
        // key = ni*16 + quad*4 + j -> chunk = ni*2+(quad>>1), within-chunk (quad&1)*4
        *(bf16x4*)&KP[pbase + (((ni*2 + (quad>>1)) ^ psw) * 8) + (quad&1)*4] = pk;
      }
      rs += __shfl_xor(rs, 16, 64);
      rs += __shfl_xor(rs, 32, 64);
      lsum[mi] += rs;
    }

    // NO barrier here: P rows [wave*32, wave*32+32) are wave-local (write+read
    // by the same wave); in-wave LDS RAW ordering handled by lgkmcnt.

    // O += P @ V   (A = P: m=q; B = V: n=d)
    #pragma unroll
    for (int ks2 = 0; ks2 < 2; ++ks2) {
      bf16x8 pf[2], vf[8];
      #pragma unroll
      for (int mi = 0; mi < 2; ++mi)
        pf[mi] = *(const bf16x8*)&KP[(wave*32 + mi*16 + lr) * 64 + (((ks2*4 + quad) ^ l7) * 8)];
      #pragma unroll
      for (int nd = 0; nd < 8; ++nd)
        vf[nd] = *(const bf16x8*)&VS[(nd*16 + lr) * 64 + (((ks2*4 + quad) ^ l7) * 8)];
      __builtin_amdgcn_s_setprio(1);
      #pragma unroll
      for (int mi = 0; mi < 2; ++mi)
        #pragma unroll
        for (int nd = 0; nd < 8; ++nd)
          accO[mi][nd] = __builtin_amdgcn_mfma_f32_16x16x32_bf16(pf[mi], vf[nd], accO[mi][nd], 0, 0, 0);
      __builtin_amdgcn_s_setprio(0);
    }
  }

  // finalize: ctx[token][h*128 + d]
  bf16_t* og = ctx + (size_t)(b * SEQ + qt * 128) * D_MODEL + h * D_HEAD;
  #pragma unroll
  for (int mi = 0; mi < 2; ++mi) {
    float inv[4];
    #pragma unroll
    for (int r = 0; r < 4; ++r) inv[r] = 1.0f / __shfl(lsum[mi], rq + r, 16);
    #pragma unroll
    for (int r = 0; r < 4; ++r) {
      int row = wave*32 + mi*16 + rq + r;
      #pragma unroll
      for (int nd = 0; nd < 8; ++nd)
        og[(size_t)row * D_MODEL + nd*16 + lr] = (bf16_t)(accO[mi][nd][r] * inv[r]);
    }
  }
}

extern "C" void kernel_launch(void* const* d_in, const int* in_sizes, int n_in,
                              void* d_out, int out_size, void* d_ws, size_t ws_size,
                              hipStream_t stream) {
  const float* x      = (const float*)d_in[0];
  const float* W_down = (const float*)d_in[1];
  const float* b_down = (const float*)d_in[2];
  const float* W_uk   = (const float*)d_in[3];
  const float* b_uk   = (const float*)d_in[4];
  const float* W_uv   = (const float*)d_in[5];
  const float* b_uv   = (const float*)d_in[6];
  const float* W_q    = (const float*)d_in[7];
  const float* b_q    = (const float*)d_in[8];
  const float* W_o    = (const float*)d_in[9];
  const float* b_o    = (const float*)d_in[10];
  float* out = (float*)d_out;

  char* ws = (char*)d_ws;
  bf16_t* xb      = (bf16_t*)ws;  ws += (size_t)MTOK*D_MODEL*2;
  bf16_t* Wt_down = (bf16_t*)ws;  ws += (size_t)D_LATENT*D_MODEL*2;
  bf16_t* Wt_uk   = (bf16_t*)ws;  ws += (size_t)D_MODEL*D_LATENT*2;
  bf16_t* Wt_uv   = (bf16_t*)ws;  ws += (size_t)D_MODEL*D_LATENT*2;
  bf16_t* Wt_q    = (bf16_t*)ws;  ws += (size_t)D_MODEL*D_MODEL*2;
  bf16_t* Wt_o    = (bf16_t*)ws;  ws += (size_t)D_MODEL*D_MODEL*2;
  bf16_t* lat     = (bf16_t*)ws;  ws += (size_t)MTOK*D_LATENT*2;
  bf16_t* keys    = (bf16_t*)ws;  ws += (size_t)MTOK*D_MODEL*2;
  bf16_t* vals    = (bf16_t*)ws;  ws += (size_t)MTOK*D_MODEL*2;
  bf16_t* qm      = (bf16_t*)ws;  ws += (size_t)MTOK*D_MODEL*2;
  bf16_t* vtm     = (bf16_t*)ws;  ws += (size_t)MTOK*D_MODEL*2;
  bf16_t* ctx     = vals;  // vals dead after transpose_v

  const float cs = 0.0883883476483184f * 1.44269504089f;  // 1/sqrt(128) * log2(e)

  convert_f32_bf16_kernel<<<(MTOK*D_MODEL/4 + 255)/256, 256, 0, stream>>>(x, xb, MTOK*D_MODEL/4);

  transpose_w_kernel<<<dim3(D_LATENT/64, D_MODEL/64), 256, 0, stream>>>(W_down, Wt_down, D_MODEL, D_LATENT);
  transpose_w_kernel<<<dim3(D_MODEL/64, D_LATENT/64), 256, 0, stream>>>(W_uk,   Wt_uk,   D_LATENT, D_MODEL);
  transpose_w_kernel<<<dim3(D_MODEL/64, D_LATENT/64), 256, 0, stream>>>(W_uv,   Wt_uv,   D_LATENT, D_MODEL);
  transpose_w_kernel<<<dim3(D_MODEL/64, D_MODEL/64),  256, 0, stream>>>(W_q,    Wt_q,    D_MODEL,  D_MODEL);
  transpose_w_kernel<<<dim3(D_MODEL/64, D_MODEL/64),  256, 0, stream>>>(W_o,    Wt_o,    D_MODEL,  D_MODEL);

  gemm_bt_kernel<bf16_t><<<dim3(MTOK/128, D_LATENT/128), 256, 0, stream>>>(xb,  Wt_down, b_down, lat,  MTOK, D_LATENT, D_MODEL, 1.0f);
  gemm_bt_kernel<bf16_t><<<dim3(MTOK/128, D_MODEL/128),  256, 0, stream>>>(lat, Wt_uk,   b_uk,   keys, MTOK, D_MODEL,  D_LATENT, 1.0f);
  gemm_bt_kernel<bf16_t><<<dim3(MTOK/128, D_MODEL/128),  256, 0, stream>>>(lat, Wt_uv,   b_uv,   vals, MTOK, D_MODEL,  D_LATENT, 1.0f);
  gemm_bt_kernel<bf16_t><<<dim3(MTOK/128, D_MODEL/128),  256, 0, stream>>>(xb,  Wt_q,    b_q,    qm,   MTOK, D_MODEL,  D_MODEL, cs);

  transpose_v_kernel<<<dim3(SEQ/64, D_HEAD/64, BATCH*NUM_HEADS), 256, 0, stream>>>(vals, vtm);

  attention_kernel<<<dim3(SEQ/128, BATCH*NUM_HEADS), 256, 0, stream>>>(qm, keys, vtm, ctx);

  gemm_bt_kernel<float><<<dim3(MTOK/128, D_MODEL/128), 256, 0, stream>>>(ctx, Wt_o, b_o, out, MTOK, D_MODEL, D_MODEL, 1.0f);
}

// Round 4
// 601.295 us; speedup vs baseline: 1.0696x; 1.0214x over previous
//
#include <hip/hip_runtime.h>

#define D_MODEL 2048
#define D_LATENT 512
#define NUM_HEADS 16
#define D_HEAD 128
#define BATCH 4
#define SEQ 2048
#define MTOK (BATCH*SEQ)   // 8192 tokens

typedef __bf16 bf16_t;
typedef __bf16 bf16x4 __attribute__((ext_vector_type(4)));
typedef __bf16 bf16x8 __attribute__((ext_vector_type(8)));
typedef float  f32x4  __attribute__((ext_vector_type(4)));

// async global->LDS, 16B per lane; LDS dst = wave-uniform base + lane*16 (m97 contract)
__device__ __forceinline__ void load_lds16(const bf16_t* g, bf16_t* l) {
  __builtin_amdgcn_global_load_lds(
      (const __attribute__((address_space(1))) void*)g,
      (__attribute__((address_space(3))) void*)l,
      16, 0, 0);
}

// ---------------- fp32 -> bf16 elementwise convert ----------------
__global__ void convert_f32_bf16_kernel(const float* __restrict__ src,
                                        bf16_t* __restrict__ dst, int n4) {
  int i = blockIdx.x * 256 + threadIdx.x;
  if (i >= n4) return;
  float4 v = *(const float4*)&src[(size_t)i * 4];
  bf16x4 o = { (bf16_t)v.x, (bf16_t)v.y, (bf16_t)v.z, (bf16_t)v.w };
  *(bf16x4*)&dst[(size_t)i * 4] = o;
}

// ------- weight transpose + convert: src f32 [R][C] -> dst bf16 [C][R] -------
__global__ void transpose_w_kernel(const float* __restrict__ src, bf16_t* __restrict__ dst,
                                   int R, int C) {
  __shared__ __align__(16) bf16_t tile[64][66];
  int rt = blockIdx.y * 64, ct = blockIdx.x * 64;
  int lc = threadIdx.x & 63, lr = threadIdx.x >> 6;
  for (int i = 0; i < 64; i += 4)
    tile[lr + i][lc] = (bf16_t)src[(size_t)(rt + lr + i) * C + ct + lc];
  __syncthreads();
  for (int i = 0; i < 64; i += 4)
    dst[(size_t)(ct + lr + i) * R + rt + lc] = tile[lc][lr + i];
}

// ------- V transpose: values bf16 [B*S][H*128] -> vt bf16 [B*H][128][S] -------
__global__ void transpose_v_kernel(const bf16_t* __restrict__ v, bf16_t* __restrict__ vt) {
  __shared__ __align__(16) bf16_t tile[64][66];
  int bh = blockIdx.z; int b = bh >> 4, h = bh & 15;
  int st = blockIdx.x * 64, dt = blockIdx.y * 64;
  int lc = threadIdx.x & 63, lr = threadIdx.x >> 6;
  const bf16_t* src = v + (size_t)b * SEQ * D_MODEL + h * D_HEAD;
  for (int i = 0; i < 64; i += 4)
    tile[lr + i][lc] = src[(size_t)(st + lr + i) * D_MODEL + dt + lc];
  __syncthreads();
  bf16_t* dst = vt + (size_t)bh * D_HEAD * SEQ;
  for (int i = 0; i < 64; i += 4)
    dst[(size_t)(dt + lr + i) * SEQ + st + lc] = tile[lc][lr + i];
}

// ---------------- GEMM: C[M][N] = (A[M][K] @ Wt[N][K]^T + bias[N]) * premul ----------------
// 128x128 tile, 4 waves, BK=32, global_load_lds width-16 staging (m97 structure).
// R2's 256^2 8-phase port regressed -> reverted permanently to this measured-good path.
template<typename OutT>
__global__ __launch_bounds__(256, 2) void gemm_bt_kernel(
    const bf16_t* __restrict__ A, const bf16_t* __restrict__ Wt,
    const float* __restrict__ bias, OutT* __restrict__ C,
    int M, int N, int K, float premul)
{
  __shared__ __align__(16) bf16_t As[128 * 32];
  __shared__ __align__(16) bf16_t Bs[128 * 32];
  int tid = threadIdx.x;
  int lane = tid & 63, wave = tid >> 6;
  int wr = (wave >> 1) * 64, wc = (wave & 1) * 64;
  size_t row0 = (size_t)blockIdx.x * 128, col0 = (size_t)blockIdx.y * 128;
  int lr = lane & 15, quad = lane >> 4, rq = quad * 4;

  f32x4 acc[4][4] = {};

  int srow = wave * 32 + (lane >> 2);
  int scol = ((lane & 3) ^ ((lane >> 3) & 3)) * 8;
  const bf16_t* Ag = A  + (row0 + srow) * K + scol;
  const bf16_t* Bg = Wt + (col0 + srow) * K + scol;
  bf16_t* Asw = As + wave * 1024;
  bf16_t* Bsw = Bs + wave * 1024;

  int rchunk = (quad ^ ((lr >> 1) & 3)) * 8;

  for (int k0 = 0; k0 < K; k0 += 32) {
    __syncthreads();
    load_lds16(Ag,          Asw);
    load_lds16(Ag + 16 * K, Asw + 512);
    load_lds16(Bg,          Bsw);
    load_lds16(Bg + 16 * K, Bsw + 512);
    Ag += 32; Bg += 32;
    __syncthreads();   // vmcnt(0) drained here -> LDS populated

    bf16x8 af[4], bfr[4];
    #pragma unroll
    for (int mi = 0; mi < 4; ++mi)
      af[mi] = *(const bf16x8*)&As[(wr + mi * 16 + lr) * 32 + rchunk];
    #pragma unroll
    for (int ni = 0; ni < 4; ++ni)
      bfr[ni] = *(const bf16x8*)&Bs[(wc + ni * 16 + lr) * 32 + rchunk];
    #pragma unroll
    for (int mi = 0; mi < 4; ++mi)
      #pragma unroll
      for (int ni = 0; ni < 4; ++ni)
        acc[mi][ni] = __builtin_amdgcn_mfma_f32_16x16x32_bf16(af[mi], bfr[ni], acc[mi][ni], 0, 0, 0);
  }

  // epilogue: C/D layout col=lane&15, row=quad*4+r  [m89-verified]
  #pragma unroll
  for (int ni = 0; ni < 4; ++ni) {
    int col = (int)col0 + wc + ni * 16 + lr;
    float bv = bias[col];
    #pragma unroll
    for (int mi = 0; mi < 4; ++mi) {
      #pragma unroll
      for (int r = 0; r < 4; ++r) {
        size_t row = row0 + wr + mi * 16 + rq + r;
        C[row * N + col] = (OutT)((acc[mi][ni][r] + bv) * premul);
      }
    }
  }
}

// ---------------- flash attention: one block per (b,h, 128 q rows) ----------------
// S^T orientation (q = lane&15); log2-domain softmax (Q pre-scaled in its GEMM).
// R4 restructure: K/V double-buffered LDS (2x16KB each) + Ps in its OWN 16KB
// region (no longer aliases Ks) -> ONE __syncthreads per K/V tile (was 3).
// Body kt: QK^T(buf cur) -> ds_write tile kt+1 (buf nxt, data prefetched last
// iter) -> issue global loads tile kt+2 -> softmax->Ps (wave-local rows, no
// barrier) -> PV(buf cur) -> barrier.  Race ledger: buf[x] writes in iter kt
// vs reads in iters kt-1 / kt+1 are separated by the end-of-body barrier in
// both directions; P rows are wave-local (in-wave lgkmcnt ordering).
// LDS 80KB -> 2 blocks/CU (matches measured residency, so no occupancy loss).
// Grid: 1D 1024 with XCD swizzle — all 16 q-tiles of one (b,h) share an XCD
// (wgid%8 == bh%8) so K/V is fetched once per XCD L2, not 8x.
// T2 XOR-swizzle kept on all LDS tiles (chunk c of row r at c^(r&7)).
__global__ __launch_bounds__(256, 2) void attention_kernel(
    const bf16_t* __restrict__ q, const bf16_t* __restrict__ keys,
    const bf16_t* __restrict__ vt, bf16_t* __restrict__ ctx)
{
  __shared__ __align__(16) bf16_t KS[2][64 * 128];   // 32KB  [key][d] swizzled
  __shared__ __align__(16) bf16_t VS[2][128 * 64];   // 32KB  [d][key] swizzled
  __shared__ __align__(16) bf16_t PS[128 * 64];      // 16KB  [q][key] swizzled
  int wg = blockIdx.x;
  int qt = (wg >> 3) & 15;
  int bh = (wg & 7) | ((wg >> 7) << 3);
  int b = bh >> 4, h = bh & 15;
  int tid = threadIdx.x, lane = tid & 63, wave = tid >> 6;
  int lr = lane & 15, quad = lane >> 4, kq = quad * 8, rq = quad * 4;
  int l7 = lr & 7;

  const bf16_t* qg = q    + (size_t)(b * SEQ + qt * 128) * D_MODEL + h * D_HEAD;
  const bf16_t* kg = keys + (size_t)b * SEQ * D_MODEL + h * D_HEAD;
  const bf16_t* vg = vt   + (size_t)bh * D_HEAD * SEQ;

  // Q fragments (B operand; layout: n=lane&15, k=quad*8+j)
  bf16x8 qf[2][4];
  #pragma unroll
  for (int mi = 0; mi < 2; ++mi)
    #pragma unroll
    for (int ks = 0; ks < 4; ++ks)
      qf[mi][ks] = *(const bf16x8*)&qg[(size_t)(wave*32 + mi*16 + lr) * D_MODEL + ks*32 + kq];

  // staging coords (LDS offsets pre-swizzled) + prefetch registers
  bf16x8 kreg[4], vreg[4];
  const bf16_t* kp4[4];
  const bf16_t* vp4[4];
  int kdo[4], vdo[4];
  #pragma unroll
  for (int i = 0; i < 4; ++i) {
    int c = tid + i * 256;
    int r = c >> 4, kc = c & 15;                    // K: 64 rows x 16 chunks
    kp4[i] = kg + (size_t)r * D_MODEL + kc * 8;
    kdo[i] = r * 128 + ((kc ^ (r & 7)) * 8);
    int d = c >> 3, vc = c & 7;                     // V: 128 rows x 8 chunks
    vp4[i] = vg + (size_t)d * SEQ + vc * 8;
    vdo[i] = d * 64 + ((vc ^ (d & 7)) * 8);
  }

  // prologue: tile 0 -> buf0 directly; then prefetch tile 1 into regs
  #pragma unroll
  for (int i = 0; i < 4; ++i) {
    kreg[i] = *(const bf16x8*)kp4[i];
    vreg[i] = *(const bf16x8*)vp4[i];
  }
  #pragma unroll
  for (int i = 0; i < 4; ++i) {
    *(bf16x8*)&KS[0][kdo[i]] = kreg[i];
    *(bf16x8*)&VS[0][vdo[i]] = vreg[i];
  }
  #pragma unroll
  for (int i = 0; i < 4; ++i) {
    kp4[i] += 64 * D_MODEL;
    vp4[i] += 64;
    kreg[i] = *(const bf16x8*)kp4[i];
    vreg[i] = *(const bf16x8*)vp4[i];
  }

  f32x4 accO[2][8] = {};                  // O[q=base+rq+r][d=nd*16+lr]
  float m2[2]   = {-1e30f, -1e30f};       // running max (log2 domain), q = base+(lane&15)
  float lsum[2] = {0.f, 0.f};

  __syncthreads();

  for (int kt = 0; kt < SEQ/64; ++kt) {
    const bf16_t* Kc = KS[kt & 1];
    const bf16_t* Vc = VS[kt & 1];
    bf16_t* Kn = KS[(kt & 1) ^ 1];
    bf16_t* Vn = VS[(kt & 1) ^ 1];

    // S^T = K @ Q^T : sc[mi][ni][r] at key=ni*16+rq+r, q=wave*32+mi*16+lr
    f32x4 sc[2][4] = {};
    #pragma unroll
    for (int ks = 0; ks < 4; ++ks) {
      bf16x8 kf[4];
      #pragma unroll
      for (int ni = 0; ni < 4; ++ni)
        kf[ni] = *(const bf16x8*)&Kc[(ni*16 + lr) * 128 + (((ks*4 + quad) ^ l7) * 8)];
      __builtin_amdgcn_s_setprio(1);
      #pragma unroll
      for (int mi = 0; mi < 2; ++mi)
        #pragma unroll
        for (int ni = 0; ni < 4; ++ni)
          sc[mi][ni] = __builtin_amdgcn_mfma_f32_16x16x32_bf16(kf[ni], qf[mi][ks], sc[mi][ni], 0, 0, 0);
      __builtin_amdgcn_s_setprio(0);
    }

    // stage tile kt+1 into the other buffer (regs loaded last iteration)
    if (kt + 1 < SEQ/64) {
      #pragma unroll
      for (int i = 0; i < 4; ++i) {
        *(bf16x8*)&Kn[kdo[i]] = kreg[i];
        *(bf16x8*)&VS[(kt & 1) ^ 1][vdo[i]] = vreg[i];
      }
    }
    (void)Vn;
    // issue global loads for tile kt+2 (depth-2 prefetch)
    if (kt + 2 < SEQ/64) {
      #pragma unroll
      for (int i = 0; i < 4; ++i) {
        kp4[i] += 64 * D_MODEL;
        vp4[i] += 64;
        kreg[i] = *(const bf16x8*)kp4[i];
        vreg[i] = *(const bf16x8*)vp4[i];
      }
    }

    // online softmax (log2 domain; scores already scaled by cs in the q-GEMM)
    #pragma unroll
    for (int mi = 0; mi < 2; ++mi) {
      float rm = sc[mi][0][0];
      #pragma unroll
      for (int ni = 0; ni < 4; ++ni)
        #pragma unroll
        for (int r = 0; r < 4; ++r) rm = fmaxf(rm, sc[mi][ni][r]);
      rm = fmaxf(rm, __shfl_xor(rm, 16, 64));
      rm = fmaxf(rm, __shfl_xor(rm, 32, 64));

      // T13 defer-max: skip rescale when the whole wave's rows grew < 2^8
      if (!__all(rm - m2[mi] <= 8.0f)) {
        float mnew  = fmaxf(m2[mi], rm);
        float alpha = exp2f(m2[mi] - mnew);
        m2[mi] = mnew;
        lsum[mi] *= alpha;
        float ar[4];
        #pragma unroll
        for (int r = 0; r < 4; ++r) ar[r] = __shfl(alpha, rq + r, 16);
        #pragma unroll
        for (int nd = 0; nd < 8; ++nd)
          #pragma unroll
          for (int r = 0; r < 4; ++r) accO[mi][nd][r] *= ar[r];
      }

      float rs = 0.f;
      int prow = wave*32 + mi*16 + lr;
      int pbase = prow * 64;
      int psw = prow & 7;
      #pragma unroll
      for (int ni = 0; ni < 4; ++ni) {
        float p0 = exp2f(sc[mi][ni][0] - m2[mi]);
        float p1 = exp2f(sc[mi][ni][1] - m2[mi]);
        float p2 = exp2f(sc[mi][ni][2] - m2[mi]);
        float p3 = exp2f(sc[mi][ni][3] - m2[mi]);
        rs += (p0 + p1) + (p2 + p3);
        bf16x4 pk = { (bf16_t)p0, (bf16_t)p1, (bf16_t)p2, (bf16_t)p3 };
        // key = ni*16 + quad*4 + j -> chunk = ni*2+(quad>>1), within-chunk (quad&1)*4
        *(bf16x4*)&PS[pbase + (((ni*2 + (quad>>1)) ^ psw) * 8) + (quad&1)*4] = pk;
      }
      rs += __shfl_xor(rs, 16, 64);
      rs += __shfl_xor(rs, 32, 64);
      lsum[mi] += rs;
    }

    // O += P @ V   (A = P: m=q; B = V: n=d)  — P rows wave-local, no barrier
    #pragma unroll
    for (int ks2 = 0; ks2 < 2; ++ks2) {
      bf16x8 pf[2], vf[8];
      #pragma unroll
      for (int mi = 0; mi < 2; ++mi)
        pf[mi] = *(const bf16x8*)&PS[(wave*32 + mi*16 + lr) * 64 + (((ks2*4 + quad) ^ l7) * 8)];
      #pragma unroll
      for (int nd = 0; nd < 8; ++nd)
        vf[nd] = *(const bf16x8*)&Vc[(nd*16 + lr) * 64 + (((ks2*4 + quad) ^ l7) * 8)];
      __builtin_amdgcn_s_setprio(1);
      #pragma unroll
      for (int mi = 0; mi < 2; ++mi)
        #pragma unroll
        for (int nd = 0; nd < 8; ++nd)
          accO[mi][nd] = __builtin_amdgcn_mfma_f32_16x16x32_bf16(pf[mi], vf[nd], accO[mi][nd], 0, 0, 0);
      __builtin_amdgcn_s_setprio(0);
    }

    __syncthreads();   // single barrier per tile: separates buf writes/reads across iters
  }

  // finalize: ctx[token][h*128 + d]
  bf16_t* og = ctx + (size_t)(b * SEQ + qt * 128) * D_MODEL + h * D_HEAD;
  #pragma unroll
  for (int mi = 0; mi < 2; ++mi) {
    float inv[4];
    #pragma unroll
    for (int r = 0; r < 4; ++r) inv[r] = 1.0f / __shfl(lsum[mi], rq + r, 16);
    #pragma unroll
    for (int r = 0; r < 4; ++r) {
      int row = wave*32 + mi*16 + rq + r;
      #pragma unroll
      for (int nd = 0; nd < 8; ++nd)
        og[(size_t)row * D_MODEL + nd*16 + lr] = (bf16_t)(accO[mi][nd][r] * inv[r]);
    }
  }
}

extern "C" void kernel_launch(void* const* d_in, const int* in_sizes, int n_in,
                              void* d_out, int out_size, void* d_ws, size_t ws_size,
                              hipStream_t stream) {
  const float* x      = (const float*)d_in[0];
  const float* W_down = (const float*)d_in[1];
  const float* b_down = (const float*)d_in[2];
  const float* W_uk   = (const float*)d_in[3];
  const float* b_uk   = (const float*)d_in[4];
  const float* W_uv   = (const float*)d_in[5];
  const float* b_uv   = (const float*)d_in[6];
  const float* W_q    = (const float*)d_in[7];
  const float* b_q    = (const float*)d_in[8];
  const float* W_o    = (const float*)d_in[9];
  const float* b_o    = (const float*)d_in[10];
  float* out = (float*)d_out;

  char* ws = (char*)d_ws;
  bf16_t* xb      = (bf16_t*)ws;  ws += (size_t)MTOK*D_MODEL*2;
  bf16_t* Wt_down = (bf16_t*)ws;  ws += (size_t)D_LATENT*D_MODEL*2;
  bf16_t* Wt_uk   = (bf16_t*)ws;  ws += (size_t)D_MODEL*D_LATENT*2;
  bf16_t* Wt_uv   = (bf16_t*)ws;  ws += (size_t)D_MODEL*D_LATENT*2;
  bf16_t* Wt_q    = (bf16_t*)ws;  ws += (size_t)D_MODEL*D_MODEL*2;
  bf16_t* Wt_o    = (bf16_t*)ws;  ws += (size_t)D_MODEL*D_MODEL*2;
  bf16_t* lat     = (bf16_t*)ws;  ws += (size_t)MTOK*D_LATENT*2;
  bf16_t* keys    = (bf16_t*)ws;  ws += (size_t)MTOK*D_MODEL*2;
  bf16_t* vals    = (bf16_t*)ws;  ws += (size_t)MTOK*D_MODEL*2;
  bf16_t* qm      = (bf16_t*)ws;  ws += (size_t)MTOK*D_MODEL*2;
  bf16_t* vtm     = (bf16_t*)ws;  ws += (size_t)MTOK*D_MODEL*2;
  bf16_t* ctx     = vals;  // vals dead after transpose_v

  const float cs = 0.0883883476483184f * 1.44269504089f;  // 1/sqrt(128) * log2(e)

  convert_f32_bf16_kernel<<<(MTOK*D_MODEL/4 + 255)/256, 256, 0, stream>>>(x, xb, MTOK*D_MODEL/4);

  transpose_w_kernel<<<dim3(D_LATENT/64, D_MODEL/64), 256, 0, stream>>>(W_down, Wt_down, D_MODEL, D_LATENT);
  transpose_w_kernel<<<dim3(D_MODEL/64, D_LATENT/64), 256, 0, stream>>>(W_uk,   Wt_uk,   D_LATENT, D_MODEL);
  transpose_w_kernel<<<dim3(D_MODEL/64, D_LATENT/64), 256, 0, stream>>>(W_uv,   Wt_uv,   D_LATENT, D_MODEL);
  transpose_w_kernel<<<dim3(D_MODEL/64, D_MODEL/64),  256, 0, stream>>>(W_q,    Wt_q,    D_MODEL,  D_MODEL);
  transpose_w_kernel<<<dim3(D_MODEL/64, D_MODEL/64),  256, 0, stream>>>(W_o,    Wt_o,    D_MODEL,  D_MODEL);

  gemm_bt_kernel<bf16_t><<<dim3(MTOK/128, D_LATENT/128), 256, 0, stream>>>(xb,  Wt_down, b_down, lat,  MTOK, D_LATENT, D_MODEL, 1.0f);
  gemm_bt_kernel<bf16_t><<<dim3(MTOK/128, D_MODEL/128),  256, 0, stream>>>(lat, Wt_uk,   b_uk,   keys, MTOK, D_MODEL,  D_LATENT, 1.0f);
  gemm_bt_kernel<bf16_t><<<dim3(MTOK/128, D_MODEL/128),  256, 0, stream>>>(lat, Wt_uv,   b_uv,   vals, MTOK, D_MODEL,  D_LATENT, 1.0f);
  gemm_bt_kernel<bf16_t><<<dim3(MTOK/128, D_MODEL/128),  256, 0, stream>>>(xb,  Wt_q,    b_q,    qm,   MTOK, D_MODEL,  D_MODEL, cs);

  transpose_v_kernel<<<dim3(SEQ/64, D_HEAD/64, BATCH*NUM_HEADS), 256, 0, stream>>>(vals, vtm);

  attention_kernel<<<1024, 256, 0, stream>>>(qm, keys, vtm, ctx);

  gemm_bt_kernel<float><<<dim3(MTOK/128, D_MODEL/128), 256, 0, stream>>>(ctx, Wt_o, b_o, out, MTOK, D_MODEL, D_MODEL, 1.0f);
}

// Round 6
// 560.854 us; speedup vs baseline: 1.1467x; 1.0721x over previous
//
#include <hip/hip_runtime.h>

#define D_MODEL 2048
#define D_LATENT 512
#define NUM_HEADS 16
#define D_HEAD 128
#define BATCH 4
#define SEQ 2048
#define MTOK (BATCH*SEQ)   // 8192 tokens

typedef __bf16 bf16_t;
typedef __bf16 bf16x4 __attribute__((ext_vector_type(4)));
typedef __bf16 bf16x8 __attribute__((ext_vector_type(8)));
typedef float  f32x4  __attribute__((ext_vector_type(4)));

// async global->LDS, 16B per lane; LDS dst = wave-uniform base + lane*16 (m97 contract)
__device__ __forceinline__ void load_lds16(const bf16_t* g, bf16_t* l) {
  __builtin_amdgcn_global_load_lds(
      (const __attribute__((address_space(1))) void*)g,
      (__attribute__((address_space(3))) void*)l,
      16, 0, 0);
}

// ---------------- fp32 -> bf16 elementwise convert ----------------
__global__ void convert_f32_bf16_kernel(const float* __restrict__ src,
                                        bf16_t* __restrict__ dst, int n4) {
  int i = blockIdx.x * 256 + threadIdx.x;
  if (i >= n4) return;
  float4 v = *(const float4*)&src[(size_t)i * 4];
  bf16x4 o = { (bf16_t)v.x, (bf16_t)v.y, (bf16_t)v.z, (bf16_t)v.w };
  *(bf16x4*)&dst[(size_t)i * 4] = o;
}

// ------- merged weight transposes: 5 matrices, one launch (z-indexed) -------
__global__ void transpose_w_all(const float* __restrict__ a0, const float* __restrict__ a1,
                                const float* __restrict__ a2, const float* __restrict__ a3,
                                const float* __restrict__ a4,
                                bf16_t* __restrict__ o0, bf16_t* __restrict__ o1,
                                bf16_t* __restrict__ o2, bf16_t* __restrict__ o3,
                                bf16_t* __restrict__ o4) {
  __shared__ __align__(16) bf16_t tile[64][66];
  int z = blockIdx.z;
  const float* src; bf16_t* dst; int R, C;
  switch (z) {
    case 0: src = a0; dst = o0; R = D_MODEL; C = D_LATENT; break;   // W_down
    case 1: src = a1; dst = o1; R = D_LATENT; C = D_MODEL; break;   // W_uk
    case 2: src = a2; dst = o2; R = D_LATENT; C = D_MODEL; break;   // W_uv
    case 3: src = a3; dst = o3; R = D_MODEL; C = D_MODEL; break;    // W_q
    default: src = a4; dst = o4; R = D_MODEL; C = D_MODEL; break;   // W_o
  }
  if ((int)blockIdx.x * 64 >= C || (int)blockIdx.y * 64 >= R) return;
  int rt = blockIdx.y * 64, ct = blockIdx.x * 64;
  int lc = threadIdx.x & 63, lr = threadIdx.x >> 6;
  for (int i = 0; i < 64; i += 4)
    tile[lr + i][lc] = (bf16_t)src[(size_t)(rt + lr + i) * C + ct + lc];
  __syncthreads();
  for (int i = 0; i < 64; i += 4)
    dst[(size_t)(ct + lr + i) * R + rt + lc] = tile[lc][lr + i];
}

// ---------------- GEMM core macro-body (m97 structure, measured-good) ----------------
// 128x128 tile, 4 waves, BK=32, global_load_lds width-16 staging.

// generic: C[M][N] = (A @ Wt^T + bias) * premul  (used for the o-projection)
template<typename OutT>
__global__ __launch_bounds__(256, 2) void gemm_bt_kernel(
    const bf16_t* __restrict__ A, const bf16_t* __restrict__ Wt,
    const float* __restrict__ bias, OutT* __restrict__ C,
    int M, int N, int K, float premul)
{
  __shared__ __align__(16) bf16_t As[128 * 32];
  __shared__ __align__(16) bf16_t Bs[128 * 32];
  int tid = threadIdx.x;
  int lane = tid & 63, wave = tid >> 6;
  int wr = (wave >> 1) * 64, wc = (wave & 1) * 64;
  size_t row0 = (size_t)blockIdx.x * 128, col0 = (size_t)blockIdx.y * 128;
  int lr = lane & 15, quad = lane >> 4, rq = quad * 4;

  f32x4 acc[4][4] = {};

  int srow = wave * 32 + (lane >> 2);
  int scol = ((lane & 3) ^ ((lane >> 3) & 3)) * 8;
  const bf16_t* Ag = A  + (row0 + srow) * K + scol;
  const bf16_t* Bg = Wt + (col0 + srow) * K + scol;
  bf16_t* Asw = As + wave * 1024;
  bf16_t* Bsw = Bs + wave * 1024;

  int rchunk = (quad ^ ((lr >> 1) & 3)) * 8;

  for (int k0 = 0; k0 < K; k0 += 32) {
    __syncthreads();
    load_lds16(Ag,          Asw);
    load_lds16(Ag + 16 * K, Asw + 512);
    load_lds16(Bg,          Bsw);
    load_lds16(Bg + 16 * K, Bsw + 512);
    Ag += 32; Bg += 32;
    __syncthreads();

    bf16x8 af[4], bfr[4];
    #pragma unroll
    for (int mi = 0; mi < 4; ++mi)
      af[mi] = *(const bf16x8*)&As[(wr + mi * 16 + lr) * 32 + rchunk];
    #pragma unroll
    for (int ni = 0; ni < 4; ++ni)
      bfr[ni] = *(const bf16x8*)&Bs[(wc + ni * 16 + lr) * 32 + rchunk];
    #pragma unroll
    for (int mi = 0; mi < 4; ++mi)
      #pragma unroll
      for (int ni = 0; ni < 4; ++ni)
        acc[mi][ni] = __builtin_amdgcn_mfma_f32_16x16x32_bf16(af[mi], bfr[ni], acc[mi][ni], 0, 0, 0);
  }

  #pragma unroll
  for (int ni = 0; ni < 4; ++ni) {
    int col = (int)col0 + wc + ni * 16 + lr;
    float bv = bias[col];
    #pragma unroll
    for (int mi = 0; mi < 4; ++mi) {
      #pragma unroll
      for (int r = 0; r < 4; ++r) {
        size_t row = row0 + wr + mi * 16 + rq + r;
        C[row * N + col] = (OutT)((acc[mi][ni][r] + bv) * premul);
      }
    }
  }
}

// fused down+q GEMM: both read xb (K=2048). blockIdx.y<4 -> lat (N=512, premul 1);
// y>=4 -> qm (N=2048, premul cs). One launch instead of two.
__global__ __launch_bounds__(256, 2) void gemm_dq_kernel(
    const bf16_t* __restrict__ A, const bf16_t* __restrict__ WtD,
    const bf16_t* __restrict__ WtQ, const float* __restrict__ biasD,
    const float* __restrict__ biasQ, bf16_t* __restrict__ CD,
    bf16_t* __restrict__ CQ, int M, float premulQ)
{
  const int K = D_MODEL;
  __shared__ __align__(16) bf16_t As[128 * 32];
  __shared__ __align__(16) bf16_t Bs[128 * 32];
  int tid = threadIdx.x;
  int lane = tid & 63, wave = tid >> 6;
  int wr = (wave >> 1) * 64, wc = (wave & 1) * 64;
  int yb = blockIdx.y;
  bool isq = yb >= 4;
  const bf16_t* Wt = isq ? WtQ : WtD;
  const float* bias = isq ? biasQ : biasD;
  bf16_t* C = isq ? CQ : CD;
  int N = isq ? D_MODEL : D_LATENT;
  float premul = isq ? premulQ : 1.0f;
  size_t row0 = (size_t)blockIdx.x * 128, col0 = (size_t)(isq ? yb - 4 : yb) * 128;
  int lr = lane & 15, quad = lane >> 4, rq = quad * 4;

  f32x4 acc[4][4] = {};

  int srow = wave * 32 + (lane >> 2);
  int scol = ((lane & 3) ^ ((lane >> 3) & 3)) * 8;
  const bf16_t* Ag = A  + (row0 + srow) * K + scol;
  const bf16_t* Bg = Wt + (col0 + srow) * K + scol;
  bf16_t* Asw = As + wave * 1024;
  bf16_t* Bsw = Bs + wave * 1024;

  int rchunk = (quad ^ ((lr >> 1) & 3)) * 8;

  for (int k0 = 0; k0 < K; k0 += 32) {
    __syncthreads();
    load_lds16(Ag,          Asw);
    load_lds16(Ag + 16 * K, Asw + 512);
    load_lds16(Bg,          Bsw);
    load_lds16(Bg + 16 * K, Bsw + 512);
    Ag += 32; Bg += 32;
    __syncthreads();

    bf16x8 af[4], bfr[4];
    #pragma unroll
    for (int mi = 0; mi < 4; ++mi)
      af[mi] = *(const bf16x8*)&As[(wr + mi * 16 + lr) * 32 + rchunk];
    #pragma unroll
    for (int ni = 0; ni < 4; ++ni)
      bfr[ni] = *(const bf16x8*)&Bs[(wc + ni * 16 + lr) * 32 + rchunk];
    #pragma unroll
    for (int mi = 0; mi < 4; ++mi)
      #pragma unroll
      for (int ni = 0; ni < 4; ++ni)
        acc[mi][ni] = __builtin_amdgcn_mfma_f32_16x16x32_bf16(af[mi], bfr[ni], acc[mi][ni], 0, 0, 0);
  }

  #pragma unroll
  for (int ni = 0; ni < 4; ++ni) {
    int col = (int)col0 + wc + ni * 16 + lr;
    float bv = bias[col];
    #pragma unroll
    for (int mi = 0; mi < 4; ++mi) {
      #pragma unroll
      for (int r = 0; r < 4; ++r) {
        size_t row = row0 + wr + mi * 16 + rq + r;
        C[row * N + col] = (bf16_t)((acc[mi][ni][r] + bv) * premul);
      }
    }
  }
}

// fused uk+uv GEMM (A=lat, K=512). blockIdx.y<16 -> keys (normal epilogue);
// y>=16 -> uv with TRANSPOSING epilogue that writes vt[bh][d][s] directly
// (kills the separate transpose_v kernel + the 128MB vals round-trip).
// Each block covers exactly one head (128 cols) x 128 tokens of one batch.
// Transposing epilogue: LDS re-tile E[64][136] (staging rows 16B-aligned:
// 136*2=272=17*16), 2 column-halves.  R5 bug fixed here: readout must drain
// 64 d-rows x SIXTEEN 16B chunks (128 s-values), not 8 — half of V^T was
// stale, absmax 3.6e-2.
__global__ __launch_bounds__(256, 2) void gemm_kv_kernel(
    const bf16_t* __restrict__ A, const bf16_t* __restrict__ WtK,
    const bf16_t* __restrict__ WtV, const float* __restrict__ biasK,
    const float* __restrict__ biasV, bf16_t* __restrict__ keysO,
    bf16_t* __restrict__ vtO, int M)
{
  const int K = D_LATENT;
  __shared__ __align__(16) bf16_t As[128 * 32];
  __shared__ __align__(16) bf16_t Bs[128 * 32];
  __shared__ __align__(16) bf16_t E[64 * 136];
  int tid = threadIdx.x;
  int lane = tid & 63, wave = tid >> 6;
  int wr = (wave >> 1) * 64, wc = (wave & 1) * 64;
  int yb = blockIdx.y;
  bool isv = yb >= 16;
  const bf16_t* Wt = isv ? WtV : WtK;
  const float* bias = isv ? biasV : biasK;
  size_t row0 = (size_t)blockIdx.x * 128, col0 = (size_t)(isv ? yb - 16 : yb) * 128;
  int lr = lane & 15, quad = lane >> 4, rq = quad * 4;

  f32x4 acc[4][4] = {};

  int srow = wave * 32 + (lane >> 2);
  int scol = ((lane & 3) ^ ((lane >> 3) & 3)) * 8;
  const bf16_t* Ag = A  + (row0 + srow) * K + scol;
  const bf16_t* Bg = Wt + (col0 + srow) * K + scol;
  bf16_t* Asw = As + wave * 1024;
  bf16_t* Bsw = Bs + wave * 1024;

  int rchunk = (quad ^ ((lr >> 1) & 3)) * 8;

  for (int k0 = 0; k0 < K; k0 += 32) {
    __syncthreads();
    load_lds16(Ag,          Asw);
    load_lds16(Ag + 16 * K, Asw + 512);
    load_lds16(Bg,          Bsw);
    load_lds16(Bg + 16 * K, Bsw + 512);
    Ag += 32; Bg += 32;
    __syncthreads();

    bf16x8 af[4], bfr[4];
    #pragma unroll
    for (int mi = 0; mi < 4; ++mi)
      af[mi] = *(const bf16x8*)&As[(wr + mi * 16 + lr) * 32 + rchunk];
    #pragma unroll
    for (int ni = 0; ni < 4; ++ni)
      bfr[ni] = *(const bf16x8*)&Bs[(wc + ni * 16 + lr) * 32 + rchunk];
    #pragma unroll
    for (int mi = 0; mi < 4; ++mi)
      #pragma unroll
      for (int ni = 0; ni < 4; ++ni)
        acc[mi][ni] = __builtin_amdgcn_mfma_f32_16x16x32_bf16(af[mi], bfr[ni], acc[mi][ni], 0, 0, 0);
  }

  if (!isv) {
    #pragma unroll
    for (int ni = 0; ni < 4; ++ni) {
      int col = (int)col0 + wc + ni * 16 + lr;
      float bv = bias[col];
      #pragma unroll
      for (int mi = 0; mi < 4; ++mi) {
        #pragma unroll
        for (int r = 0; r < 4; ++r) {
          size_t row = row0 + wr + mi * 16 + rq + r;
          keysO[row * D_MODEL + col] = (bf16_t)(acc[mi][ni][r] + bv);
        }
      }
    }
  } else {
    // tokens row0..row0+127 lie within one batch (2048 | 128): b = row0>>11
    int b = (int)(row0 >> 11);
    int s0 = (int)(row0 & 2047);
    int h = yb - 16;
    bf16_t* vtb = vtO + (size_t)(b * NUM_HEADS + h) * D_HEAD * SEQ;
    #pragma unroll
    for (int h2 = 0; h2 < 2; ++h2) {
      __syncthreads();
      if ((wave & 1) == h2) {
        // this wave's cols = [h2*64, h2*64+64); stage E[d_half][s]
        #pragma unroll
        for (int ni = 0; ni < 4; ++ni) {
          int dh = ni * 16 + lr;                        // 0..63 within half
          float bv = bias[(int)col0 + h2 * 64 + dh];
          #pragma unroll
          for (int mi = 0; mi < 4; ++mi) {
            #pragma unroll
            for (int r = 0; r < 4; ++r) {
              int s = wr + mi * 16 + rq + r;            // 0..127
              E[dh * 136 + s] = (bf16_t)(acc[mi][ni][r] + bv);
            }
          }
        }
      }
      __syncthreads();
      // readout: 64 d-rows x 16 chunks of 16B (full 128 s-values), coalesced
      for (int t = tid; t < 1024; t += 256) {
        int d = t >> 4, ch = t & 15;
        bf16x8 v = *(const bf16x8*)&E[d * 136 + ch * 8];
        *(bf16x8*)&vtb[(size_t)(h2 * 64 + d) * SEQ + s0 + ch * 8] = v;
      }
    }
  }
}

// ---------------- flash attention (unchanged from R4-best) ----------------
__global__ __launch_bounds__(256, 2) void attention_kernel(
    const bf16_t* __restrict__ q, const bf16_t* __restrict__ keys,
    const bf16_t* __restrict__ vt, bf16_t* __restrict__ ctx)
{
  __shared__ __align__(16) bf16_t KS[2][64 * 128];   // 32KB  [key][d] swizzled
  __shared__ __align__(16) bf16_t VS[2][128 * 64];   // 32KB  [d][key] swizzled
  __shared__ __align__(16) bf16_t PS[128 * 64];      // 16KB  [q][key] swizzled
  int wg = blockIdx.x;
  int qt = (wg >> 3) & 15;
  int bh = (wg & 7) | ((wg >> 7) << 3);
  int b = bh >> 4, h = bh & 15;
  int tid = threadIdx.x, lane = tid & 63, wave = tid >> 6;
  int lr = lane & 15, quad = lane >> 4, kq = quad * 8, rq = quad * 4;
  int l7 = lr & 7;

  const bf16_t* qg = q    + (size_t)(b * SEQ + qt * 128) * D_MODEL + h * D_HEAD;
  const bf16_t* kg = keys + (size_t)b * SEQ * D_MODEL + h * D_HEAD;
  const bf16_t* vg = vt   + (size_t)bh * D_HEAD * SEQ;

  bf16x8 qf[2][4];
  #pragma unroll
  for (int mi = 0; mi < 2; ++mi)
    #pragma unroll
    for (int ks = 0; ks < 4; ++ks)
      qf[mi][ks] = *(const bf16x8*)&qg[(size_t)(wave*32 + mi*16 + lr) * D_MODEL + ks*32 + kq];

  bf16x8 kreg[4], vreg[4];
  const bf16_t* kp4[4];
  const bf16_t* vp4[4];
  int kdo[4], vdo[4];
  #pragma unroll
  for (int i = 0; i < 4; ++i) {
    int c = tid + i * 256;
    int r = c >> 4, kc = c & 15;
    kp4[i] = kg + (size_t)r * D_MODEL + kc * 8;
    kdo[i] = r * 128 + ((kc ^ (r & 7)) * 8);
    int d = c >> 3, vc = c & 7;
    vp4[i] = vg + (size_t)d * SEQ + vc * 8;
    vdo[i] = d * 64 + ((vc ^ (d & 7)) * 8);
  }

  #pragma unroll
  for (int i = 0; i < 4; ++i) {
    kreg[i] = *(const bf16x8*)kp4[i];
    vreg[i] = *(const bf16x8*)vp4[i];
  }
  #pragma unroll
  for (int i = 0; i < 4; ++i) {
    *(bf16x8*)&KS[0][kdo[i]] = kreg[i];
    *(bf16x8*)&VS[0][vdo[i]] = vreg[i];
  }
  #pragma unroll
  for (int i = 0; i < 4; ++i) {
    kp4[i] += 64 * D_MODEL;
    vp4[i] += 64;
    kreg[i] = *(const bf16x8*)kp4[i];
    vreg[i] = *(const bf16x8*)vp4[i];
  }

  f32x4 accO[2][8] = {};
  float m2[2]   = {-1e30f, -1e30f};
  float lsum[2] = {0.f, 0.f};

  __syncthreads();

  for (int kt = 0; kt < SEQ/64; ++kt) {
    const bf16_t* Kc = KS[kt & 1];
    const bf16_t* Vc = VS[kt & 1];
    bf16_t* Kn = KS[(kt & 1) ^ 1];

    f32x4 sc[2][4] = {};
    #pragma unroll
    for (int ks = 0; ks < 4; ++ks) {
      bf16x8 kf[4];
      #pragma unroll
      for (int ni = 0; ni < 4; ++ni)
        kf[ni] = *(const bf16x8*)&Kc[(ni*16 + lr) * 128 + (((ks*4 + quad) ^ l7) * 8)];
      __builtin_amdgcn_s_setprio(1);
      #pragma unroll
      for (int mi = 0; mi < 2; ++mi)
        #pragma unroll
        for (int ni = 0; ni < 4; ++ni)
          sc[mi][ni] = __builtin_amdgcn_mfma_f32_16x16x32_bf16(kf[ni], qf[mi][ks], sc[mi][ni], 0, 0, 0);
      __builtin_amdgcn_s_setprio(0);
    }

    if (kt + 1 < SEQ/64) {
      #pragma unroll
      for (int i = 0; i < 4; ++i) {
        *(bf16x8*)&Kn[kdo[i]] = kreg[i];
        *(bf16x8*)&VS[(kt & 1) ^ 1][vdo[i]] = vreg[i];
      }
    }
    if (kt + 2 < SEQ/64) {
      #pragma unroll
      for (int i = 0; i < 4; ++i) {
        kp4[i] += 64 * D_MODEL;
        vp4[i] += 64;
        kreg[i] = *(const bf16x8*)kp4[i];
        vreg[i] = *(const bf16x8*)vp4[i];
      }
    }

    #pragma unroll
    for (int mi = 0; mi < 2; ++mi) {
      float rm = sc[mi][0][0];
      #pragma unroll
      for (int ni = 0; ni < 4; ++ni)
        #pragma unroll
        for (int r = 0; r < 4; ++r) rm = fmaxf(rm, sc[mi][ni][r]);
      rm = fmaxf(rm, __shfl_xor(rm, 16, 64));
      rm = fmaxf(rm, __shfl_xor(rm, 32, 64));

      if (!__all(rm - m2[mi] <= 8.0f)) {
        float mnew  = fmaxf(m2[mi], rm);
        float alpha = exp2f(m2[mi] - mnew);
        m2[mi] = mnew;
        lsum[mi] *= alpha;
        float ar[4];
        #pragma unroll
        for (int r = 0; r < 4; ++r) ar[r] = __shfl(alpha, rq + r, 16);
        #pragma unroll
        for (int nd = 0; nd < 8; ++nd)
          #pragma unroll
          for (int r = 0; r < 4; ++r) accO[mi][nd][r] *= ar[r];
      }

      float rs = 0.f;
      int prow = wave*32 + mi*16 + lr;
      int pbase = prow * 64;
      int psw = prow & 7;
      #pragma unroll
      for (int ni = 0; ni < 4; ++ni) {
        float p0 = exp2f(sc[mi][ni][0] - m2[mi]);
        float p1 = exp2f(sc[mi][ni][1] - m2[mi]);
        float p2 = exp2f(sc[mi][ni][2] - m2[mi]);
        float p3 = exp2f(sc[mi][ni][3] - m2[mi]);
        rs += (p0 + p1) + (p2 + p3);
        bf16x4 pk = { (bf16_t)p0, (bf16_t)p1, (bf16_t)p2, (bf16_t)p3 };
        *(bf16x4*)&PS[pbase + (((ni*2 + (quad>>1)) ^ psw) * 8) + (quad&1)*4] = pk;
      }
      rs += __shfl_xor(rs, 16, 64);
      rs += __shfl_xor(rs, 32, 64);
      lsum[mi] += rs;
    }

    #pragma unroll
    for (int ks2 = 0; ks2 < 2; ++ks2) {
      bf16x8 pf[2], vf[8];
      #pragma unroll
      for (int mi = 0; mi < 2; ++mi)
        pf[mi] = *(const bf16x8*)&PS[(wave*32 + mi*16 + lr) * 64 + (((ks2*4 + quad) ^ l7) * 8)];
      #pragma unroll
      for (int nd = 0; nd < 8; ++nd)
        vf[nd] = *(const bf16x8*)&Vc[(nd*16 + lr) * 64 + (((ks2*4 + quad) ^ l7) * 8)];
      __builtin_amdgcn_s_setprio(1);
      #pragma unroll
      for (int mi = 0; mi < 2; ++mi)
        #pragma unroll
        for (int nd = 0; nd < 8; ++nd)
          accO[mi][nd] = __builtin_amdgcn_mfma_f32_16x16x32_bf16(pf[mi], vf[nd], accO[mi][nd], 0, 0, 0);
      __builtin_amdgcn_s_setprio(0);
    }

    __syncthreads();
  }

  bf16_t* og = ctx + (size_t)(b * SEQ + qt * 128) * D_MODEL + h * D_HEAD;
  #pragma unroll
  for (int mi = 0; mi < 2; ++mi) {
    float inv[4];
    #pragma unroll
    for (int r = 0; r < 4; ++r) inv[r] = 1.0f / __shfl(lsum[mi], rq + r, 16);
    #pragma unroll
    for (int r = 0; r < 4; ++r) {
      int row = wave*32 + mi*16 + rq + r;
      #pragma unroll
      for (int nd = 0; nd < 8; ++nd)
        og[(size_t)row * D_MODEL + nd*16 + lr] = (bf16_t)(accO[mi][nd][r] * inv[r]);
    }
  }
}

extern "C" void kernel_launch(void* const* d_in, const int* in_sizes, int n_in,
                              void* d_out, int out_size, void* d_ws, size_t ws_size,
                              hipStream_t stream) {
  const float* x      = (const float*)d_in[0];
  const float* W_down = (const float*)d_in[1];
  const float* b_down = (const float*)d_in[2];
  const float* W_uk   = (const float*)d_in[3];
  const float* b_uk   = (const float*)d_in[4];
  const float* W_uv   = (const float*)d_in[5];
  const float* b_uv   = (const float*)d_in[6];
  const float* W_q    = (const float*)d_in[7];
  const float* b_q    = (const float*)d_in[8];
  const float* W_o    = (const float*)d_in[9];
  const float* b_o    = (const float*)d_in[10];
  float* out = (float*)d_out;

  char* ws = (char*)d_ws;
  bf16_t* xb      = (bf16_t*)ws;  ws += (size_t)MTOK*D_MODEL*2;
  bf16_t* Wt_down = (bf16_t*)ws;  ws += (size_t)D_LATENT*D_MODEL*2;
  bf16_t* Wt_uk   = (bf16_t*)ws;  ws += (size_t)D_MODEL*D_LATENT*2;
  bf16_t* Wt_uv   = (bf16_t*)ws;  ws += (size_t)D_MODEL*D_LATENT*2;
  bf16_t* Wt_q    = (bf16_t*)ws;  ws += (size_t)D_MODEL*D_MODEL*2;
  bf16_t* Wt_o    = (bf16_t*)ws;  ws += (size_t)D_MODEL*D_MODEL*2;
  bf16_t* lat     = (bf16_t*)ws;  ws += (size_t)MTOK*D_LATENT*2;
  bf16_t* keys    = (bf16_t*)ws;  ws += (size_t)MTOK*D_MODEL*2;
  bf16_t* vals    = (bf16_t*)ws;  ws += (size_t)MTOK*D_MODEL*2;  // ctx only
  bf16_t* qm      = (bf16_t*)ws;  ws += (size_t)MTOK*D_MODEL*2;
  bf16_t* vtm     = (bf16_t*)ws;  ws += (size_t)MTOK*D_MODEL*2;
  bf16_t* ctx     = vals;  // vals never materialized (uv GEMM writes vtm directly)

  const float cs = 0.0883883476483184f * 1.44269504089f;  // 1/sqrt(128) * log2(e)

  convert_f32_bf16_kernel<<<(MTOK*D_MODEL/4 + 255)/256, 256, 0, stream>>>(x, xb, MTOK*D_MODEL/4);

  transpose_w_all<<<dim3(32, 32, 5), 256, 0, stream>>>(
      W_down, W_uk, W_uv, W_q, W_o, Wt_down, Wt_uk, Wt_uv, Wt_q, Wt_o);

  // fused down + q (both read xb, K=2048)
  gemm_dq_kernel<<<dim3(MTOK/128, 4 + D_MODEL/128), 256, 0, stream>>>(
      xb, Wt_down, Wt_q, b_down, b_q, lat, qm, MTOK, cs);

  // fused uk + uv (both read lat, K=512); uv half writes vt layout directly
  gemm_kv_kernel<<<dim3(MTOK/128, 32), 256, 0, stream>>>(
      lat, Wt_uk, Wt_uv, b_uk, b_uv, keys, vtm, MTOK);

  attention_kernel<<<1024, 256, 0, stream>>>(qm, keys, vtm, ctx);

  gemm_bt_kernel<float><<<dim3(MTOK/128, D_MODEL/128), 256, 0, stream>>>(ctx, Wt_o, b_o, out, MTOK, D_MODEL, D_MODEL, 1.0f);
}